// Round 14
// baseline (828.346 us; speedup 1.0000x reference)
//
#include <hip/hip_runtime.h>

typedef __bf16 bf16;
typedef bf16 bf16x4 __attribute__((ext_vector_type(4)));
typedef bf16 bf16x8 __attribute__((ext_vector_type(8)));
typedef float f32x4 __attribute__((ext_vector_type(4)));
typedef unsigned long u64x2 __attribute__((ext_vector_type(2)));
typedef int i32x8 __attribute__((ext_vector_type(8)));

#define AS1 __attribute__((address_space(1)))
#define AS3 __attribute__((address_space(3)))

#define B_ 2048
#define T_ 80
#define E_ 100
#define H_ 512
#define TC_ 8               // time-chunk (serial rnn steps = T + 3*TC = 104)
#define NC_ (T_ / TC_)      // 10 chunks
#define ROWS_ 16            // rnn: 16 batch rows/block -> 48.75KB LDS -> 2 blocks/CU
#define L_ 4

// R13: MX GEMM retry with the R11 spill fixed. R11 PROVED the
// mfma_scale_f32_16x16x128_f8f6f4 chunk-stacked layout (absmax 0.0) but
// (256,4) capped VGPR at 128 -> acc spill (WRITE 225MB). Now: double-buffered
// BK=128 (2x32KB, LDS 66560 -> 2 blk/CU) + launch_bounds(256,2) -> 256 VGPR.
// fp8 datapath (R4) + coalesced staging (R5) + XOR swizzle (R7) + rnn VALU
// diet (R8) + rnn 2-blk/CU (R10).
// SEQ8 is TIME-MAJOR fp8 h*16: seq8[(t*B_ + b)*H_ + h]  (e4m3)
// W8[l] is n-major fp8 W*64: W8[n*Kp + k]
// GEMM: xw = (x8 @ W8^T) / (sx*64), sx=16 (h) or 256 (embed); xwc stays bf16.
// MX tile LDS (per buffer): A[128 rows][128 k-bytes] at +0, B at +16384.
// 3-bit granule XOR involution: phys granule g holds source g ^ (r&7),
// staged via pre-swizzled global source; readers XOR the same.
// U fp8 A-OPERAND layout (unchanged, operand-swapped rnn):
//   byte[lane*16 + half*8 + j] = U[k=(2p+half)*32+(lane>>4)*8+j][ht*16+(lane&15)] * 2^6

// raw v_exp_f32 + x16 h-scale folded into the fma: returns 16*tanh(x).
__device__ __forceinline__ float tanh16(float x) {
  float e = __builtin_amdgcn_exp2f(x * 2.8853900817779268f);  // e^{2x}
  return 16.f - 32.f * __builtin_amdgcn_rcpf(e + 1.f);
}

__device__ __forceinline__ long pack_fp8x8(const float* f) {
  int w0 = __builtin_amdgcn_cvt_pk_fp8_f32(f[0], f[1], 0, false);
  w0 = __builtin_amdgcn_cvt_pk_fp8_f32(f[2], f[3], w0, true);
  int w1 = __builtin_amdgcn_cvt_pk_fp8_f32(f[4], f[5], 0, false);
  w1 = __builtin_amdgcn_cvt_pk_fp8_f32(f[6], f[7], w1, true);
  return (long)(((unsigned long)(unsigned)w1 << 32) | (unsigned)w0);
}

// ---- Merged weight conversion (2 launches) ----

struct WConv {
  const float* src[4];
  unsigned char* dst[4];
  int K[4];
  int Kp[4];
};

// W8[n][k] = W[k][n] * 64 as fp8, one 8-k group per thread
__global__ void convert_weight_all(WConv wc) {
  int layer = blockIdx.y;
  int idx = blockIdx.x * 256 + threadIdx.x;
  int K = wc.K[layer], Kp = wc.Kp[layer];
  int gpr = Kp >> 3;
  if (idx >= 512 * gpr) return;
  int n = idx / gpr, k0 = (idx - n * gpr) * 8;
  float f[8];
#pragma unroll
  for (int j = 0; j < 8; j++) {
    int k = k0 + j;
    f[j] = (k < K) ? wc.src[layer][(long)k * 512 + n] * 64.f : 0.f;
  }
  *(long*)(wc.dst[layer] + (long)n * Kp + k0) = pack_fp8x8(f);
}

struct UConv {
  const float* src[4];
  unsigned char* dst[4];
};

__global__ void convert_u_all(UConv uc) {
  int layer = blockIdx.y;
  int idx = blockIdx.x * 256 + threadIdx.x;
  int half = idx & 1, lane = (idx >> 1) & 63, p = (idx >> 7) & 7, ht = idx >> 10;
  int q = lane >> 4;
  int k0 = (2 * p + half) * 32 + q * 8;
  int n = ht * 16 + (lane & 15);
  float f[8];
#pragma unroll
  for (int j = 0; j < 8; j++) f[j] = uc.src[layer][(long)(k0 + j) * H_ + n] * 64.f;
  *(long*)(uc.dst[layer] + (long)(ht * 8 + p) * 1024 + lane * 16 + half * 8) = pack_fp8x8(f);
}

// ---- GEMM tiles (256-thread block, 66560B LDS, 2 blocks/CU) ----

#define SROW_ 136  // C-stage row stride in bf16 (272 B)
#define GSMEM_ 66560

// MX K=512 tile: 4 iters of BK=128, double-buffered. Per iter: 8 DMA insts
// (16x64B segments each), 16 mfma_scale (K=128) per wave, 1 barrier.
__device__ __forceinline__ void gemm_tile8_mx(
    const unsigned char* __restrict__ A8, const unsigned char* __restrict__ B8,
    bf16* __restrict__ C, int mtile, int ntile, int stid, char* base) {
  const int K = 512;
  const int wave = stid >> 6, lane = stid & 63;
  const int l = lane & 15, q = lane >> 4;
  const long m0 = (long)mtile * 128;
  const int n0 = ntile * 128;
  const int wm = (wave >> 1) * 64, wn = (wave & 1) * 64;

  f32x4 acc[4][4] = {};

  // staging map: slot s = stid + 256*j covers row r = s>>3, granule g = s&7;
  // pre-swizzled source granule = g ^ (r&7)  (3-bit involution)
  const unsigned char* Asrc[4];
  const unsigned char* Bsrc[4];
#pragma unroll
  for (int j = 0; j < 4; j++) {
    int s = stid + 256 * j;
    int r = s >> 3, g = s & 7;
    int sg = g ^ (r & 7);
    Asrc[j] = A8 + (m0 + r) * K + sg * 16;
    Bsrc[j] = B8 + (long)(n0 + r) * K + sg * 16;
  }

  auto issue = [&](int i) {  // stage K-block [i*128, i*128+128) into buf[i&1]
    char* bb = base + (i & 1) * 32768;
    int k0 = i * 128;
#pragma unroll
    for (int j = 0; j < 4; j++) {
      __builtin_amdgcn_global_load_lds((const AS1 void*)(Asrc[j] + k0),
                                       (AS3 void*)(bb + (stid + 256 * j) * 16), 16, 0, 0);
      __builtin_amdgcn_global_load_lds((const AS1 void*)(Bsrc[j] + k0),
                                       (AS3 void*)(bb + 16384 + (stid + 256 * j) * 16), 16, 0, 0);
    }
  };

  const int qh = q >> 1, qb = (q & 1) * 8, lsw = l & 7;
  const int sc1 = 0x7f7f7f7f;  // e8m0 = 127 -> scale 1.0 for all blocks

  issue(0);
  __syncthreads();  // buf0 ready
  for (int i = 0; i < 4; i++) {
    if (i + 1 < 4) issue(i + 1);  // overlaps compute; drains at barrier
    const char* bb = base + (i & 1) * 32768;
    // B fragments: 4 n-frags x v8i32 (chunk c -> regs 2c,2c+1)
    i32x8 bv[4];
#pragma unroll
    for (int j = 0; j < 4; j++) {
      const char* rb = bb + 16384 + (wn + j * 16 + l) * 128;
#pragma unroll
      for (int c = 0; c < 4; c++) {
        long v = *(const long*)(rb + (((2 * c + qh) ^ lsw) * 16) + qb);
        bv[j][2 * c] = (int)(unsigned)v;
        bv[j][2 * c + 1] = (int)(unsigned)(v >> 32);
      }
    }
#pragma unroll
    for (int i2 = 0; i2 < 4; i2++) {
      const char* ra = bb + (wm + i2 * 16 + l) * 128;
      i32x8 av;
#pragma unroll
      for (int c = 0; c < 4; c++) {
        long v = *(const long*)(ra + (((2 * c + qh) ^ lsw) * 16) + qb);
        av[2 * c] = (int)(unsigned)v;
        av[2 * c + 1] = (int)(unsigned)(v >> 32);
      }
#pragma unroll
      for (int j = 0; j < 4; j++)
        acc[i2][j] = __builtin_amdgcn_mfma_scale_f32_16x16x128_f8f6f4(
            av, bv[j], acc[i2][j], 0, 0, 0, sc1, 0, sc1);
    }
    __syncthreads();  // drains issue(i+1); protects buf reuse
  }
  // LDS-staged coalesced store, dequant 1/(16*64)
  bf16* stage = (bf16*)base;
#pragma unroll
  for (int ph = 0; ph < 2; ph++) {
    if (wm == ph * 64) {
#pragma unroll
      for (int i = 0; i < 4; i++)
#pragma unroll
        for (int j = 0; j < 4; j++)
#pragma unroll
          for (int r = 0; r < 4; r++)
            stage[(i * 16 + q * 4 + r) * SROW_ + wn + j * 16 + l] =
                (bf16)(acc[i][j][r] * 0.0009765625f);
    }
    __syncthreads();
#pragma unroll
    for (int pass = 0; pass < 4; pass++) {
      int u = pass * 256 + stid;
      int row = u >> 4, seg = u & 15;
      bf16x8 v = *(const bf16x8*)(stage + row * SROW_ + seg * 8);
      *(bf16x8*)(C + (m0 + ph * 64 + row) * (long)H_ + n0 + seg * 8) = v;
    }
    __syncthreads();
  }
}

// layer-1 tile with fused embedding gather -> fp8 (x256); K=128 (2 BK=64 iters)
// (unchanged from R10/R12: 16x16x32 fp8, double-buffered 2x16KB, 2-term XOR)
__device__ __forceinline__ void gemm_tile_embed8(
    const int* __restrict__ tokens, const float* __restrict__ emb,
    const unsigned char* __restrict__ B8, bf16* __restrict__ xwc, int t0,
    int mtile, int ntile, int stid, char* base) {
  int* stok = (int*)(base + 32768);  // above embed's 2x16KB staging
  const int K = 128;
  const int wave = stid >> 6, lane = stid & 63;
  const int l = lane & 15, q = lane >> 4;
  const int trow = mtile >> 4;
  const int b0 = (mtile & 15) * 128;
  const int t = t0 + trow;
  const int n0 = ntile * 128;
  const int wm = (wave >> 1) * 64, wn = (wave & 1) * 64;

  if (stid < 128) stok[stid] = tokens[(b0 + stid) * T_ + t];
  __syncthreads();

  f32x4 acc[4][4] = {};

  const int sr2 = stid >> 2, c4 = stid & 3;
  const int swz = c4 ^ (sr2 & 3) ^ ((sr2 >> 2) & 3);
  const unsigned char* Bsrc0 = B8 + (long)(n0 + sr2) * K + swz * 16;
  const unsigned char* Bsrc1 = B8 + (long)(n0 + 64 + sr2) * K + swz * 16;
  const float* er0 = emb + (long)stok[sr2] * E_;
  const float* er1 = emb + (long)stok[64 + sr2] * E_;

  auto issue = [&](int i) {  // B DMA + A emb-gather->fp8 for K-block i
    char* bb = base + (i & 1) * 16384;
    int k0 = i * 64;
    __builtin_amdgcn_global_load_lds((const AS1 void*)(Bsrc0 + k0),
                                     (AS3 void*)(bb + 8192 + stid * 16), 16, 0, 0);
    __builtin_amdgcn_global_load_lds((const AS1 void*)(Bsrc1 + k0),
                                     (AS3 void*)(bb + 12288 + stid * 16), 16, 0, 0);
    int kb = k0 + swz * 16;
    float f[16];
    u64x2 v;
#pragma unroll
    for (int j = 0; j < 16; j++) {
      int k = kb + j;
      f[j] = (k < E_) ? er0[k] * 256.f : 0.f;
    }
    v.x = (unsigned long)pack_fp8x8(f);
    v.y = (unsigned long)pack_fp8x8(f + 8);
    *(u64x2*)(bb + stid * 16) = v;
#pragma unroll
    for (int j = 0; j < 16; j++) {
      int k = kb + j;
      f[j] = (k < E_) ? er1[k] * 256.f : 0.f;
    }
    v.x = (unsigned long)pack_fp8x8(f);
    v.y = (unsigned long)pack_fp8x8(f + 8);
    *(u64x2*)(bb + 4096 + stid * 16) = v;
  };

  const int qh = q >> 1, qb = (q & 1) * 8;
  const int lswz = (l & 3) ^ ((l >> 2) & 3);

  issue(0);
  __syncthreads();
  for (int i = 0; i < 2; i++) {
    if (i + 1 < 2) issue(i + 1);
    const char* bb = base + (i & 1) * 16384;
#pragma unroll
    for (int ks = 0; ks < 2; ks++) {
      const int go = (((ks * 2 + qh) ^ lswz) * 16) + qb;
      long af[4], bf[4];
#pragma unroll
      for (int i2 = 0; i2 < 4; i2++) {
        af[i2] = *(const long*)(bb + (wm + i2 * 16 + l) * 64 + go);
        bf[i2] = *(const long*)(bb + 8192 + (wn + i2 * 16 + l) * 64 + go);
      }
#pragma unroll
      for (int i2 = 0; i2 < 4; i2++)
#pragma unroll
        for (int j = 0; j < 4; j++)
          acc[i2][j] = __builtin_amdgcn_mfma_f32_16x16x32_fp8_fp8(af[i2], bf[j], acc[i2][j], 0, 0, 0);
    }
    __syncthreads();
  }
  // LDS-staged coalesced store, dequant 1/(256*64)
  bf16* C = xwc + ((long)trow * B_ + b0) * H_;
  bf16* stage = (bf16*)base;
#pragma unroll
  for (int ph = 0; ph < 2; ph++) {
    if (wm == ph * 64) {
#pragma unroll
      for (int i = 0; i < 4; i++)
#pragma unroll
        for (int j = 0; j < 4; j++)
#pragma unroll
          for (int r = 0; r < 4; r++)
            stage[(i * 16 + q * 4 + r) * SROW_ + wn + j * 16 + l] =
                (bf16)(acc[i][j][r] * 6.103515625e-5f);
    }
    __syncthreads();
#pragma unroll
    for (int pass = 0; pass < 4; pass++) {
      int u = pass * 256 + stid;
      int row = u >> 4, seg = u & 15;
      bf16x8 v = *(const bf16x8*)(stage + row * SROW_ + seg * 8);
      *(bf16x8*)(C + (long)(ph * 64 + row) * H_ + n0 + seg * 8) = v;
    }
    __syncthreads();
  }
}

struct GemmTasks {
  const unsigned char* A[4];
  const unsigned char* Bt[4];
  bf16* C[4];
  int kind[4];
  int t0[4];
};

// 512 tiles per task; block -> (task, tile).
// launch_bounds(256,2): 256-VGPR budget (no acc spill); LDS 66560 -> 2 blk/CU.
__global__ __launch_bounds__(256, 2) void gemm_multi(
    GemmTasks gt, const int* __restrict__ tokens, const float* __restrict__ emb) {
  __shared__ __align__(16) char smem[GSMEM_];
  const int task = blockIdx.x >> 9;
  const int tile = blockIdx.x & 511;
  const int mt = tile & 127, ntl = tile >> 7;
  if (gt.kind[task] == 1)
    gemm_tile_embed8(tokens, emb, gt.Bt[task], gt.C[task], gt.t0[task], mt, ntl,
                     threadIdx.x, smem);
  else
    gemm_tile8_mx(gt.A[task], gt.Bt[task], gt.C[task], mt, ntl, threadIdx.x, smem);
}

struct RnnTasks {
  const bf16* xwc[4];
  const unsigned char* U8[4];
  const float* bias[4];
  int t0[4];
  int first[4];
};

// rnn sync discipline (R2/R3, kept):
//   - epilogue guarded by counted vmcnt: retires prefetch(tl) but leaves this
//     step's seq-store (+ prefetch(tl+1) when present) in flight.
//   - barrier = lgkmcnt(0) + raw s_barrier.
#define RNN_VMW(n) asm volatile("s_waitcnt vmcnt(" #n ")" ::: "memory")
#define RNN_BAR()                                      \
  do {                                                 \
    __builtin_amdgcn_sched_barrier(0);                 \
    asm volatile("s_waitcnt lgkmcnt(0)" ::: "memory"); \
    __builtin_amdgcn_s_barrier();                      \
    __builtin_amdgcn_sched_barrier(0);                 \
  } while (0)

// Multi-task recurrent chunk (R10): 128 blocks/task x 1024 thr, block = 16
// batch rows -> 48.75KB LDS -> 2 blocks/CU (32 waves); co-resident blocks
// drift out of phase so one's MFMA covers the other's epilogue/barrier.
__global__ __launch_bounds__(1024) void rnn_multi(RnnTasks rt, unsigned char* __restrict__ seq8) {
  __shared__ __align__(16) char smem[49920];
  char* hls8 = smem;                    // 2 x (16 x 520 B) fp8 h
  bf16* xws = (bf16*)(smem + 16640);    // 2 x (16 x 520) bf16 xw in
  const int task = blockIdx.x >> 7;
  const int blk = blockIdx.x & 127;
  const bf16* xwc = rt.xwc[task];
  const unsigned char* U8 = rt.U8[task];
  const float* bias = rt.bias[task];
  const int t0 = rt.t0[task];
  const int first = rt.first[task];
  const int tid = threadIdx.x;
  const int wave = tid >> 6, lane = tid & 63;
  const int l = lane & 15, q = lane >> 4;
  const int b0 = blk * ROWS_;

  // preload this wave's U slice into registers (hidden-tiles wave*2, wave*2+1)
  const unsigned char* Ub = U8 + (long)(wave * 2) * 8192 + lane * 16;
  u64x2 Ureg[8][2];
#pragma unroll
  for (int kk2 = 0; kk2 < 8; kk2++)
#pragma unroll
    for (int nt = 0; nt < 2; nt++)
      Ureg[kk2][nt] = *(const u64x2*)(Ub + nt * 8192 + kk2 * 1024);

  // init h_{t0-1} into hls8[0]: direct fp8 copy from seq8 (1 row/wave)
  {
    long pk = 0;
    if (!first)
      pk = *(const long*)(seq8 + ((long)(t0 - 1) * B_ + b0 + wave) * H_ + lane * 8);
    *(long*)(hls8 + wave * 520 + lane * 8) = pk;
  }

  // bias indexed by hidden = (wave*2+nt)*16 + q*4 + r
  float bb[2][4];
#pragma unroll
  for (int nt = 0; nt < 2; nt++)
#pragma unroll
    for (int r = 0; r < 4; r++)
      bb[nt][r] = bias[(wave * 2 + nt) * 16 + q * 4 + r];

  auto prefetch = [&](int tl2) {  // 1 row/wave (row = wave)
    int buf = tl2 & 1;
    __builtin_amdgcn_global_load_lds(
        (const AS1 void*)(xwc + ((long)tl2 * B_ + b0 + wave) * H_ + lane * 8),
        (AS3 void*)(xws + (buf * ROWS_ + wave) * 520), 16, 0, 0);
  };

  prefetch(0);
  __syncthreads();  // full drain once: xws buf 0 ready; hls8[0] visible

  for (int tl = 0; tl < TC_; tl++) {
    // store h(tl-1) from hls8[tl&1] (it is this step's B-operand too; RAR ok)
    if (tl > 0) {
      *(long*)(seq8 + ((long)(t0 + tl - 1) * B_ + b0 + wave) * H_ + lane * 8) =
          *(const long*)(hls8 + ((tl & 1) * ROWS_ + wave) * 520 + lane * 8);
    }
    if (tl + 1 < TC_) prefetch(tl + 1);  // lands by epilogue(tl+1)'s vmcnt

    const char* hb = hls8 + ((tl & 1) * ROWS_ + l) * 520 + q * 8;
    f32x4 acc[2] = {};
#pragma unroll
    for (int kk2 = 0; kk2 < 8; kk2++) {
      long ha = *(const long*)(hb + kk2 * 64);
      long hbv = *(const long*)(hb + kk2 * 64 + 32);
#pragma unroll
      for (int nt = 0; nt < 2; nt++) {
        acc[nt] = __builtin_amdgcn_mfma_f32_16x16x32_fp8_fp8((long)Ureg[kk2][nt].x, ha,
                                                             acc[nt], 0, 0, 0);
        acc[nt] = __builtin_amdgcn_mfma_f32_16x16x32_fp8_fp8((long)Ureg[kk2][nt].y, hbv,
                                                             acc[nt], 0, 0, 0);
      }
    }
    // epilogue: read xw (bf16), tanh16, write fp8 h into hls8[(tl+1)&1].
    // counted vmcnt: prefetch(tl) retired; newest [store(1), prefetch(1)]
    // stay in flight. Last step has no prefetch -> vmcnt(1).
    if (tl + 1 < TC_) RNN_VMW(2); else RNN_VMW(1);
#pragma unroll
    for (int nt = 0; nt < 2; nt++) {
      int hoff = (wave * 2 + nt) * 16 + q * 4;
      const bf16* xp = xws + ((tl & 1) * ROWS_ + l) * 520 + hoff;
      bf16x4 xv = *(const bf16x4*)xp;
      float hv16[4];
#pragma unroll
      for (int r = 0; r < 4; r++)
        hv16[r] = tanh16((float)xv[r] + bb[nt][r] + acc[nt][r] * 0.0009765625f);
      unsigned pw = (unsigned)__builtin_amdgcn_cvt_pk_fp8_f32(
          hv16[0], hv16[1], 0, false);
      pw = (unsigned)__builtin_amdgcn_cvt_pk_fp8_f32(
          hv16[2], hv16[3], (int)pw, true);
      *(unsigned*)(hls8 + (((tl + 1) & 1) * ROWS_ + l) * 520 + hoff) = pw;
    }
    RNN_BAR();  // lgkmcnt(0) only: LDS writes visible; globals float
  }
  // final step's store: h(t0+TC-1) lives in hls8[TC_&1]
  {
    *(long*)(seq8 + ((long)(t0 + TC_ - 1) * B_ + b0 + wave) * H_ + lane * 8) =
        *(const long*)(hls8 + ((TC_ & 1) * ROWS_ + wave) * 520 + lane * 8);
  }
}

// out[b] = sigmoid(dot(h_fp8[b]/16, Wo) + bo)
__global__ __launch_bounds__(256) void head_kernel(
    const unsigned char* __restrict__ seq8, const float* __restrict__ Wo,
    const float* __restrict__ bo, float* __restrict__ out) {
  int wave = threadIdx.x >> 6, lane = threadIdx.x & 63;
  int row = blockIdx.x * 4 + wave;
  const unsigned char* p = seq8 + ((long)(T_ - 1) * B_ + row) * H_ + lane * 8;
  int w0 = *(const int*)p;
  int w1 = *(const int*)(p + 4);
  const float* wp = Wo + lane * 8;
  float s = 0.f;
  s += __builtin_amdgcn_cvt_f32_fp8(w0, 0) * wp[0];
  s += __builtin_amdgcn_cvt_f32_fp8(w0, 1) * wp[1];
  s += __builtin_amdgcn_cvt_f32_fp8(w0, 2) * wp[2];
  s += __builtin_amdgcn_cvt_f32_fp8(w0, 3) * wp[3];
  s += __builtin_amdgcn_cvt_f32_fp8(w1, 0) * wp[4];
  s += __builtin_amdgcn_cvt_f32_fp8(w1, 1) * wp[5];
  s += __builtin_amdgcn_cvt_f32_fp8(w1, 2) * wp[6];
  s += __builtin_amdgcn_cvt_f32_fp8(w1, 3) * wp[7];
  s *= 0.0625f;  // /16 h-scale
#pragma unroll
  for (int off = 32; off; off >>= 1) s += __shfl_down(s, off, 64);
  if (lane == 0) {
    float x = s + bo[0];
    out[row] = 1.f / (1.f + exp2f(-x * 1.44269504088896f));
  }
}

extern "C" void kernel_launch(void* const* d_in, const int* in_sizes, int n_in,
                              void* d_out, int out_size, void* d_ws, size_t ws_size,
                              hipStream_t stream) {
  (void)in_sizes; (void)n_in; (void)out_size;
  const int*   tokens = (const int*)d_in[0];
  const float* emb = (const float*)d_in[1];
  const float* Ws[4] = {(const float*)d_in[2], (const float*)d_in[5],
                        (const float*)d_in[8], (const float*)d_in[11]};
  const float* Us[4] = {(const float*)d_in[3], (const float*)d_in[6],
                        (const float*)d_in[9], (const float*)d_in[12]};
  const float* bs[4] = {(const float*)d_in[4], (const float*)d_in[7],
                        (const float*)d_in[10], (const float*)d_in[13]};
  const float* Wo = (const float*)d_in[14];
  const float* bo = (const float*)d_in[15];
  float* out = (float*)d_out;

  char* w = (char*)d_ws;
  const size_t SEQ8_BYTES = (size_t)T_ * B_ * H_;              // 80 MB fp8
  const size_t W8_BYTES = 512 * 128 + 3 * 512 * 512;           // 832 KB
  const size_t U8_BYTES = 4 * 512 * 512;                       // 1 MB
  const size_t XWB = (size_t)TC_ * B_ * H_ * 2;                // 16 MB bf16
  const bool wf = ws_size >= SEQ8_BYTES + W8_BYTES + U8_BYTES + 4 * XWB;  // ~146 MB

  unsigned char* SEQ8 = (unsigned char*)w;
  unsigned char* W8[4];
  W8[0] = (unsigned char*)(w + SEQ8_BYTES);
  W8[1] = W8[0] + 512 * 128;
  W8[2] = W8[1] + 512 * 512;
  W8[3] = W8[2] + 512 * 512;
  unsigned char* Up[4];
  Up[0] = W8[3] + 512 * 512;
  Up[1] = Up[0] + 512 * 512;
  Up[2] = Up[1] + 512 * 512;
  Up[3] = Up[2] + 512 * 512;
  char* bankbase = w + SEQ8_BYTES + W8_BYTES + U8_BYTES;
  bf16* BANK[4];
  for (int i = 0; i < 4; i++) BANK[i] = (bf16*)(bankbase + (size_t)i * XWB);

  {
    WConv wc{};
    UConv uc{};
    for (int i = 0; i < 4; i++) {
      wc.src[i] = Ws[i]; wc.dst[i] = W8[i];
      wc.K[i] = (i == 0) ? 100 : 512;
      wc.Kp[i] = (i == 0) ? 128 : 512;
      uc.src[i] = Us[i]; uc.dst[i] = Up[i];
    }
    convert_weight_all<<<dim3(128, 4), 256, 0, stream>>>(wc);
    convert_u_all<<<dim3(128, 4), 256, 0, stream>>>(uc);
  }

  if (wf) {
    // layer-wavefront: round r = gemm then rnn for tasks (l, c=r-l), bank per layer.
    for (int r = 0; r <= NC_ - 1 + L_ - 1; r++) {
      GemmTasks gt{};
      RnnTasks rt{};
      int n = 0;
      int lmin = r - (NC_ - 1); if (lmin < 0) lmin = 0;
      int lmax = r < L_ - 1 ? r : L_ - 1;
      for (int l = lmin; l <= lmax; l++) {
        int c = r - l;
        bf16* xb = BANK[l];
        gt.A[n] = SEQ8 + (size_t)c * TC_ * B_ * H_;
        gt.Bt[n] = W8[l];
        gt.C[n] = xb;
        gt.kind[n] = (l == 0) ? 1 : 2;
        gt.t0[n] = c * TC_;
        rt.xwc[n] = xb;
        rt.U8[n] = Up[l];
        rt.bias[n] = bs[l];
        rt.t0[n] = c * TC_;
        rt.first[n] = (c == 0) ? 1 : 0;
        n++;
      }
      gemm_multi<<<n * 512, 256, 0, stream>>>(gt, tokens, emb);
      rnn_multi<<<n * 128, 1024, 0, stream>>>(rt, SEQ8);
    }
  } else {
    // serial fallback: 2 banks
    for (int l = 0; l < L_; l++) {
      for (int c = 0; c < NC_; c++) {
        bf16* xb = BANK[c & 1];
        GemmTasks gt{};
        RnnTasks rt{};
        gt.A[0] = SEQ8 + (size_t)c * TC_ * B_ * H_;
        gt.Bt[0] = W8[l];
        gt.C[0] = xb;
        gt.kind[0] = (l == 0) ? 1 : 2;
        gt.t0[0] = c * TC_;
        rt.xwc[0] = xb;
        rt.U8[0] = Up[l];
        rt.bias[0] = bs[l];
        rt.t0[0] = c * TC_;
        rt.first[0] = (c == 0) ? 1 : 0;
        gemm_multi<<<512, 256, 0, stream>>>(gt, tokens, emb);
        rnn_multi<<<128, 1024, 0, stream>>>(rt, SEQ8);
      }
    }
  }

  head_kernel<<<B_ / 4, 256, 0, stream>>>(SEQ8, Wo, bo, out);
}

// Round 15
// 768.286 us; speedup vs baseline: 1.0782x; 1.0782x over previous
//
#include <hip/hip_runtime.h>

typedef __bf16 bf16;
typedef bf16 bf16x4 __attribute__((ext_vector_type(4)));
typedef bf16 bf16x8 __attribute__((ext_vector_type(8)));
typedef float f32x4 __attribute__((ext_vector_type(4)));
typedef unsigned long u64x2 __attribute__((ext_vector_type(2)));

#define AS1 __attribute__((address_space(1)))
#define AS3 __attribute__((address_space(3)))

#define B_ 2048
#define T_ 80
#define E_ 100
#define H_ 512
#define TC_ 8               // time-chunk (serial rnn steps = T + 3*TC = 104)
#define NC_ (T_ / TC_)      // 10 chunks
#define ROWS_ 16            // rnn: 16 batch rows/block -> 48.75KB LDS -> 2 blocks/CU
#define L_ 4

// R14: final revert to the best-measured config (R10/R12, 770.9-797.6us).
// MX K=128 branch closed: R11 (spilled, 4 blk/CU) and R13 (no spill, 2 blk/CU)
// both slower than plain fp8 16x16x32 at this tile geometry — fewer waves +
// longer-latency mfma_scale ops -> latency-bound (R13: MfmaUtil 10.5%).
// fp8 datapath (R4) + coalesced BK=64 staging (R5) + 2-term XOR swizzle (R7)
// + rnn VALU diet / bh-split (R8) + rnn 2-blocks/CU phase interleave (R10).
// SEQ8 is TIME-MAJOR fp8 h*16: seq8[(t*B_ + b)*H_ + h]  (e4m3)
// W8[l] is n-major fp8 W*64: W8[n*Kp + k]
// GEMM: xw = (x8 @ W8^T) / (sx*64), sx=16 (h) or 256 (embed); xwc stays bf16.
// LDS tile (A or B): [128 rows][64 k-bytes], granule-XOR involution
// phys(r, c) holds source granule c ^ (r&3) ^ ((r>>2)&3), staged by
// global_load_lds with pre-swizzled global source; readers XOR the same.
// U fp8 A-OPERAND layout (unchanged, operand-swapped rnn):
//   byte[lane*16 + half*8 + j] = U[k=(2p+half)*32+(lane>>4)*8+j][ht*16+(lane&15)] * 2^6

// raw v_exp_f32 + x16 h-scale folded into the fma: returns 16*tanh(x).
__device__ __forceinline__ float tanh16(float x) {
  float e = __builtin_amdgcn_exp2f(x * 2.8853900817779268f);  // e^{2x}
  return 16.f - 32.f * __builtin_amdgcn_rcpf(e + 1.f);
}

__device__ __forceinline__ long pack_fp8x8(const float* f) {
  int w0 = __builtin_amdgcn_cvt_pk_fp8_f32(f[0], f[1], 0, false);
  w0 = __builtin_amdgcn_cvt_pk_fp8_f32(f[2], f[3], w0, true);
  int w1 = __builtin_amdgcn_cvt_pk_fp8_f32(f[4], f[5], 0, false);
  w1 = __builtin_amdgcn_cvt_pk_fp8_f32(f[6], f[7], w1, true);
  return (long)(((unsigned long)(unsigned)w1 << 32) | (unsigned)w0);
}

// ---- Merged weight conversion (2 launches) ----

struct WConv {
  const float* src[4];
  unsigned char* dst[4];
  int K[4];
  int Kp[4];
};

// W8[n][k] = W[k][n] * 64 as fp8, one 8-k group per thread
__global__ void convert_weight_all(WConv wc) {
  int layer = blockIdx.y;
  int idx = blockIdx.x * 256 + threadIdx.x;
  int K = wc.K[layer], Kp = wc.Kp[layer];
  int gpr = Kp >> 3;
  if (idx >= 512 * gpr) return;
  int n = idx / gpr, k0 = (idx - n * gpr) * 8;
  float f[8];
#pragma unroll
  for (int j = 0; j < 8; j++) {
    int k = k0 + j;
    f[j] = (k < K) ? wc.src[layer][(long)k * 512 + n] * 64.f : 0.f;
  }
  *(long*)(wc.dst[layer] + (long)n * Kp + k0) = pack_fp8x8(f);
}

struct UConv {
  const float* src[4];
  unsigned char* dst[4];
};

__global__ void convert_u_all(UConv uc) {
  int layer = blockIdx.y;
  int idx = blockIdx.x * 256 + threadIdx.x;
  int half = idx & 1, lane = (idx >> 1) & 63, p = (idx >> 7) & 7, ht = idx >> 10;
  int q = lane >> 4;
  int k0 = (2 * p + half) * 32 + q * 8;
  int n = ht * 16 + (lane & 15);
  float f[8];
#pragma unroll
  for (int j = 0; j < 8; j++) f[j] = uc.src[layer][(long)(k0 + j) * H_ + n] * 64.f;
  *(long*)(uc.dst[layer] + (long)(ht * 8 + p) * 1024 + lane * 16 + half * 8) = pack_fp8x8(f);
}

// ---- fp8 GEMM tile device functions (256-thread block, 35840B LDS) ----
// BK=64, double-buffered 2x16KB staging; 4 blocks/CU. Per iter: 4 DMA insts
// (16x64B segments each), 32 MFMA, 1 barrier (8 iters for K=512).

#define SROW_ 136  // C-stage row stride in bf16 (272 B)
#define GSMEM_ 35840

__device__ __forceinline__ void gemm_tile8(
    const unsigned char* __restrict__ A8, const unsigned char* __restrict__ B8,
    bf16* __restrict__ C, int mtile, int ntile, int stid, char* base) {
  const int K = 512;
  const int wave = stid >> 6, lane = stid & 63;
  const int l = lane & 15, q = lane >> 4;
  const long m0 = (long)mtile * 128;
  const int n0 = ntile * 128;
  const int wm = (wave >> 1) * 64, wn = (wave & 1) * 64;

  f32x4 acc[4][4] = {};

  // staging: thread covers rows sr2 and 64+sr2 (A and B), granule c4,
  // pre-swizzled source granule swz = c4 ^ (r&3) ^ ((r>>2)&3)
  const int sr2 = stid >> 2, c4 = stid & 3;
  const int swz = c4 ^ (sr2 & 3) ^ ((sr2 >> 2) & 3);
  const unsigned char* Asrc0 = A8 + (m0 + sr2) * K + swz * 16;
  const unsigned char* Asrc1 = A8 + (m0 + 64 + sr2) * K + swz * 16;
  const unsigned char* Bsrc0 = B8 + (long)(n0 + sr2) * K + swz * 16;
  const unsigned char* Bsrc1 = B8 + (long)(n0 + 64 + sr2) * K + swz * 16;

  auto issue = [&](int i) {  // stage K-block [i*64, i*64+64) into buf[i&1]
    char* bb = base + (i & 1) * 16384;
    int k0 = i * 64;
    __builtin_amdgcn_global_load_lds((const AS1 void*)(Asrc0 + k0),
                                     (AS3 void*)(bb + stid * 16), 16, 0, 0);
    __builtin_amdgcn_global_load_lds((const AS1 void*)(Asrc1 + k0),
                                     (AS3 void*)(bb + 4096 + stid * 16), 16, 0, 0);
    __builtin_amdgcn_global_load_lds((const AS1 void*)(Bsrc0 + k0),
                                     (AS3 void*)(bb + 8192 + stid * 16), 16, 0, 0);
    __builtin_amdgcn_global_load_lds((const AS1 void*)(Bsrc1 + k0),
                                     (AS3 void*)(bb + 12288 + stid * 16), 16, 0, 0);
  };

  // reader granule perm: (k-granule) ^ (l&3) ^ ((l>>2)&3)
  const int qh = q >> 1, qb = (q & 1) * 8;
  const int lswz = (l & 3) ^ ((l >> 2) & 3);

  issue(0);
  __syncthreads();  // buf0 ready
  for (int i = 0; i < 8; i++) {
    if (i + 1 < 8) issue(i + 1);  // overlaps compute; drains at barrier
    const char* bb = base + (i & 1) * 16384;
#pragma unroll
    for (int ks = 0; ks < 2; ks++) {
      const int go = (((ks * 2 + qh) ^ lswz) * 16) + qb;
      long af[4], bf[4];
#pragma unroll
      for (int i2 = 0; i2 < 4; i2++) {
        af[i2] = *(const long*)(bb + (wm + i2 * 16 + l) * 64 + go);
        bf[i2] = *(const long*)(bb + 8192 + (wn + i2 * 16 + l) * 64 + go);
      }
#pragma unroll
      for (int i2 = 0; i2 < 4; i2++)
#pragma unroll
        for (int j = 0; j < 4; j++)
          acc[i2][j] = __builtin_amdgcn_mfma_f32_16x16x32_fp8_fp8(af[i2], bf[j], acc[i2][j], 0, 0, 0);
    }
    __syncthreads();  // drains issue(i+1); protects buf reuse
  }
  // LDS-staged coalesced store, dequant 1/(16*64)
  bf16* stage = (bf16*)base;
#pragma unroll
  for (int ph = 0; ph < 2; ph++) {
    if (wm == ph * 64) {
#pragma unroll
      for (int i = 0; i < 4; i++)
#pragma unroll
        for (int j = 0; j < 4; j++)
#pragma unroll
          for (int r = 0; r < 4; r++)
            stage[(i * 16 + q * 4 + r) * SROW_ + wn + j * 16 + l] =
                (bf16)(acc[i][j][r] * 0.0009765625f);
    }
    __syncthreads();
#pragma unroll
    for (int pass = 0; pass < 4; pass++) {
      int u = pass * 256 + stid;
      int row = u >> 4, seg = u & 15;
      bf16x8 v = *(const bf16x8*)(stage + row * SROW_ + seg * 8);
      *(bf16x8*)(C + (m0 + ph * 64 + row) * (long)H_ + n0 + seg * 8) = v;
    }
    __syncthreads();
  }
}

// layer-1 tile with fused embedding gather -> fp8 (x256); K=128 (2 BK=64 iters)
__device__ __forceinline__ void gemm_tile_embed8(
    const int* __restrict__ tokens, const float* __restrict__ emb,
    const unsigned char* __restrict__ B8, bf16* __restrict__ xwc, int t0,
    int mtile, int ntile, int stid, char* base) {
  int* stok = (int*)(base + 32768);  // above both staging buffers; dead by epilogue
  const int K = 128;
  const int wave = stid >> 6, lane = stid & 63;
  const int l = lane & 15, q = lane >> 4;
  const int trow = mtile >> 4;
  const int b0 = (mtile & 15) * 128;
  const int t = t0 + trow;
  const int n0 = ntile * 128;
  const int wm = (wave >> 1) * 64, wn = (wave & 1) * 64;

  if (stid < 128) stok[stid] = tokens[(b0 + stid) * T_ + t];
  __syncthreads();

  f32x4 acc[4][4] = {};

  const int sr2 = stid >> 2, c4 = stid & 3;
  const int swz = c4 ^ (sr2 & 3) ^ ((sr2 >> 2) & 3);
  const unsigned char* Bsrc0 = B8 + (long)(n0 + sr2) * K + swz * 16;
  const unsigned char* Bsrc1 = B8 + (long)(n0 + 64 + sr2) * K + swz * 16;
  const float* er0 = emb + (long)stok[sr2] * E_;
  const float* er1 = emb + (long)stok[64 + sr2] * E_;

  auto issue = [&](int i) {  // B DMA + A emb-gather->fp8 for K-block i
    char* bb = base + (i & 1) * 16384;
    int k0 = i * 64;
    __builtin_amdgcn_global_load_lds((const AS1 void*)(Bsrc0 + k0),
                                     (AS3 void*)(bb + 8192 + stid * 16), 16, 0, 0);
    __builtin_amdgcn_global_load_lds((const AS1 void*)(Bsrc1 + k0),
                                     (AS3 void*)(bb + 12288 + stid * 16), 16, 0, 0);
    int kb = k0 + swz * 16;
    float f[16];
    u64x2 v;
#pragma unroll
    for (int j = 0; j < 16; j++) {
      int k = kb + j;
      f[j] = (k < E_) ? er0[k] * 256.f : 0.f;
    }
    v.x = (unsigned long)pack_fp8x8(f);
    v.y = (unsigned long)pack_fp8x8(f + 8);
    *(u64x2*)(bb + stid * 16) = v;
#pragma unroll
    for (int j = 0; j < 16; j++) {
      int k = kb + j;
      f[j] = (k < E_) ? er1[k] * 256.f : 0.f;
    }
    v.x = (unsigned long)pack_fp8x8(f);
    v.y = (unsigned long)pack_fp8x8(f + 8);
    *(u64x2*)(bb + 4096 + stid * 16) = v;
  };

  const int qh = q >> 1, qb = (q & 1) * 8;
  const int lswz = (l & 3) ^ ((l >> 2) & 3);

  issue(0);
  __syncthreads();
  for (int i = 0; i < 2; i++) {
    if (i + 1 < 2) issue(i + 1);
    const char* bb = base + (i & 1) * 16384;
#pragma unroll
    for (int ks = 0; ks < 2; ks++) {
      const int go = (((ks * 2 + qh) ^ lswz) * 16) + qb;
      long af[4], bf[4];
#pragma unroll
      for (int i2 = 0; i2 < 4; i2++) {
        af[i2] = *(const long*)(bb + (wm + i2 * 16 + l) * 64 + go);
        bf[i2] = *(const long*)(bb + 8192 + (wn + i2 * 16 + l) * 64 + go);
      }
#pragma unroll
      for (int i2 = 0; i2 < 4; i2++)
#pragma unroll
        for (int j = 0; j < 4; j++)
          acc[i2][j] = __builtin_amdgcn_mfma_f32_16x16x32_fp8_fp8(af[i2], bf[j], acc[i2][j], 0, 0, 0);
    }
    __syncthreads();
  }
  // LDS-staged coalesced store, dequant 1/(256*64)
  bf16* C = xwc + ((long)trow * B_ + b0) * H_;
  bf16* stage = (bf16*)base;
#pragma unroll
  for (int ph = 0; ph < 2; ph++) {
    if (wm == ph * 64) {
#pragma unroll
      for (int i = 0; i < 4; i++)
#pragma unroll
        for (int j = 0; j < 4; j++)
#pragma unroll
          for (int r = 0; r < 4; r++)
            stage[(i * 16 + q * 4 + r) * SROW_ + wn + j * 16 + l] =
                (bf16)(acc[i][j][r] * 6.103515625e-5f);
    }
    __syncthreads();
#pragma unroll
    for (int pass = 0; pass < 4; pass++) {
      int u = pass * 256 + stid;
      int row = u >> 4, seg = u & 15;
      bf16x8 v = *(const bf16x8*)(stage + row * SROW_ + seg * 8);
      *(bf16x8*)(C + (long)(ph * 64 + row) * H_ + n0 + seg * 8) = v;
    }
    __syncthreads();
  }
}

struct GemmTasks {
  const unsigned char* A[4];
  const unsigned char* Bt[4];
  bf16* C[4];
  int kind[4];
  int t0[4];
};

// 512 tiles per task; block -> (task, tile)
__global__ __launch_bounds__(256, 4) void gemm_multi(
    GemmTasks gt, const int* __restrict__ tokens, const float* __restrict__ emb) {
  __shared__ __align__(16) char smem[GSMEM_];
  const int task = blockIdx.x >> 9;
  const int tile = blockIdx.x & 511;
  const int mt = tile & 127, ntl = tile >> 7;
  if (gt.kind[task] == 1)
    gemm_tile_embed8(tokens, emb, gt.Bt[task], gt.C[task], gt.t0[task], mt, ntl,
                     threadIdx.x, smem);
  else
    gemm_tile8(gt.A[task], gt.Bt[task], gt.C[task], mt, ntl, threadIdx.x, smem);
}

struct RnnTasks {
  const bf16* xwc[4];
  const unsigned char* U8[4];
  const float* bias[4];
  int t0[4];
  int first[4];
};

// rnn sync discipline (R2/R3, kept):
//   - epilogue guarded by counted vmcnt: retires prefetch(tl) but leaves this
//     step's seq-store (+ prefetch(tl+1) when present) in flight.
//   - barrier = lgkmcnt(0) + raw s_barrier.
#define RNN_VMW(n) asm volatile("s_waitcnt vmcnt(" #n ")" ::: "memory")
#define RNN_BAR()                                      \
  do {                                                 \
    __builtin_amdgcn_sched_barrier(0);                 \
    asm volatile("s_waitcnt lgkmcnt(0)" ::: "memory"); \
    __builtin_amdgcn_s_barrier();                      \
    __builtin_amdgcn_sched_barrier(0);                 \
  } while (0)

// Multi-task recurrent chunk (R10): 128 blocks/task x 1024 thr, block = 16
// batch rows -> 48.75KB LDS -> 2 blocks/CU (32 waves); co-resident blocks
// drift out of phase so one's MFMA covers the other's epilogue/barrier.
__global__ __launch_bounds__(1024) void rnn_multi(RnnTasks rt, unsigned char* __restrict__ seq8) {
  __shared__ __align__(16) char smem[49920];
  char* hls8 = smem;                    // 2 x (16 x 520 B) fp8 h
  bf16* xws = (bf16*)(smem + 16640);    // 2 x (16 x 520) bf16 xw in
  const int task = blockIdx.x >> 7;
  const int blk = blockIdx.x & 127;
  const bf16* xwc = rt.xwc[task];
  const unsigned char* U8 = rt.U8[task];
  const float* bias = rt.bias[task];
  const int t0 = rt.t0[task];
  const int first = rt.first[task];
  const int tid = threadIdx.x;
  const int wave = tid >> 6, lane = tid & 63;
  const int l = lane & 15, q = lane >> 4;
  const int b0 = blk * ROWS_;

  // preload this wave's U slice into registers (hidden-tiles wave*2, wave*2+1)
  const unsigned char* Ub = U8 + (long)(wave * 2) * 8192 + lane * 16;
  u64x2 Ureg[8][2];
#pragma unroll
  for (int kk2 = 0; kk2 < 8; kk2++)
#pragma unroll
    for (int nt = 0; nt < 2; nt++)
      Ureg[kk2][nt] = *(const u64x2*)(Ub + nt * 8192 + kk2 * 1024);

  // init h_{t0-1} into hls8[0]: direct fp8 copy from seq8 (1 row/wave)
  {
    long pk = 0;
    if (!first)
      pk = *(const long*)(seq8 + ((long)(t0 - 1) * B_ + b0 + wave) * H_ + lane * 8);
    *(long*)(hls8 + wave * 520 + lane * 8) = pk;
  }

  // bias indexed by hidden = (wave*2+nt)*16 + q*4 + r
  float bb[2][4];
#pragma unroll
  for (int nt = 0; nt < 2; nt++)
#pragma unroll
    for (int r = 0; r < 4; r++)
      bb[nt][r] = bias[(wave * 2 + nt) * 16 + q * 4 + r];

  auto prefetch = [&](int tl2) {  // 1 row/wave (row = wave)
    int buf = tl2 & 1;
    __builtin_amdgcn_global_load_lds(
        (const AS1 void*)(xwc + ((long)tl2 * B_ + b0 + wave) * H_ + lane * 8),
        (AS3 void*)(xws + (buf * ROWS_ + wave) * 520), 16, 0, 0);
  };

  prefetch(0);
  __syncthreads();  // full drain once: xws buf 0 ready; hls8[0] visible

  for (int tl = 0; tl < TC_; tl++) {
    // store h(tl-1) from hls8[tl&1] (it is this step's B-operand too; RAR ok)
    if (tl > 0) {
      *(long*)(seq8 + ((long)(t0 + tl - 1) * B_ + b0 + wave) * H_ + lane * 8) =
          *(const long*)(hls8 + ((tl & 1) * ROWS_ + wave) * 520 + lane * 8);
    }
    if (tl + 1 < TC_) prefetch(tl + 1);  // lands by epilogue(tl+1)'s vmcnt

    const char* hb = hls8 + ((tl & 1) * ROWS_ + l) * 520 + q * 8;
    f32x4 acc[2] = {};
#pragma unroll
    for (int kk2 = 0; kk2 < 8; kk2++) {
      long ha = *(const long*)(hb + kk2 * 64);
      long hbv = *(const long*)(hb + kk2 * 64 + 32);
#pragma unroll
      for (int nt = 0; nt < 2; nt++) {
        acc[nt] = __builtin_amdgcn_mfma_f32_16x16x32_fp8_fp8((long)Ureg[kk2][nt].x, ha,
                                                             acc[nt], 0, 0, 0);
        acc[nt] = __builtin_amdgcn_mfma_f32_16x16x32_fp8_fp8((long)Ureg[kk2][nt].y, hbv,
                                                             acc[nt], 0, 0, 0);
      }
    }
    // epilogue: read xw (bf16), tanh16, write fp8 h into hls8[(tl+1)&1].
    // counted vmcnt: prefetch(tl) retired; newest [store(1), prefetch(1)]
    // stay in flight. Last step has no prefetch -> vmcnt(1).
    if (tl + 1 < TC_) RNN_VMW(2); else RNN_VMW(1);
#pragma unroll
    for (int nt = 0; nt < 2; nt++) {
      int hoff = (wave * 2 + nt) * 16 + q * 4;
      const bf16* xp = xws + ((tl & 1) * ROWS_ + l) * 520 + hoff;
      bf16x4 xv = *(const bf16x4*)xp;
      float hv16[4];
#pragma unroll
      for (int r = 0; r < 4; r++)
        hv16[r] = tanh16((float)xv[r] + bb[nt][r] + acc[nt][r] * 0.0009765625f);
      unsigned pw = (unsigned)__builtin_amdgcn_cvt_pk_fp8_f32(
          hv16[0], hv16[1], 0, false);
      pw = (unsigned)__builtin_amdgcn_cvt_pk_fp8_f32(
          hv16[2], hv16[3], (int)pw, true);
      *(unsigned*)(hls8 + (((tl + 1) & 1) * ROWS_ + l) * 520 + hoff) = pw;
    }
    RNN_BAR();  // lgkmcnt(0) only: LDS writes visible; globals float
  }
  // final step's store: h(t0+TC-1) lives in hls8[TC_&1]
  {
    *(long*)(seq8 + ((long)(t0 + TC_ - 1) * B_ + b0 + wave) * H_ + lane * 8) =
        *(const long*)(hls8 + ((TC_ & 1) * ROWS_ + wave) * 520 + lane * 8);
  }
}

// out[b] = sigmoid(dot(h_fp8[b]/16, Wo) + bo)
__global__ __launch_bounds__(256) void head_kernel(
    const unsigned char* __restrict__ seq8, const float* __restrict__ Wo,
    const float* __restrict__ bo, float* __restrict__ out) {
  int wave = threadIdx.x >> 6, lane = threadIdx.x & 63;
  int row = blockIdx.x * 4 + wave;
  const unsigned char* p = seq8 + ((long)(T_ - 1) * B_ + row) * H_ + lane * 8;
  int w0 = *(const int*)p;
  int w1 = *(const int*)(p + 4);
  const float* wp = Wo + lane * 8;
  float s = 0.f;
  s += __builtin_amdgcn_cvt_f32_fp8(w0, 0) * wp[0];
  s += __builtin_amdgcn_cvt_f32_fp8(w0, 1) * wp[1];
  s += __builtin_amdgcn_cvt_f32_fp8(w0, 2) * wp[2];
  s += __builtin_amdgcn_cvt_f32_fp8(w0, 3) * wp[3];
  s += __builtin_amdgcn_cvt_f32_fp8(w1, 0) * wp[4];
  s += __builtin_amdgcn_cvt_f32_fp8(w1, 1) * wp[5];
  s += __builtin_amdgcn_cvt_f32_fp8(w1, 2) * wp[6];
  s += __builtin_amdgcn_cvt_f32_fp8(w1, 3) * wp[7];
  s *= 0.0625f;  // /16 h-scale
#pragma unroll
  for (int off = 32; off; off >>= 1) s += __shfl_down(s, off, 64);
  if (lane == 0) {
    float x = s + bo[0];
    out[row] = 1.f / (1.f + exp2f(-x * 1.44269504088896f));
  }
}

extern "C" void kernel_launch(void* const* d_in, const int* in_sizes, int n_in,
                              void* d_out, int out_size, void* d_ws, size_t ws_size,
                              hipStream_t stream) {
  (void)in_sizes; (void)n_in; (void)out_size;
  const int*   tokens = (const int*)d_in[0];
  const float* emb = (const float*)d_in[1];
  const float* Ws[4] = {(const float*)d_in[2], (const float*)d_in[5],
                        (const float*)d_in[8], (const float*)d_in[11]};
  const float* Us[4] = {(const float*)d_in[3], (const float*)d_in[6],
                        (const float*)d_in[9], (const float*)d_in[12]};
  const float* bs[4] = {(const float*)d_in[4], (const float*)d_in[7],
                        (const float*)d_in[10], (const float*)d_in[13]};
  const float* Wo = (const float*)d_in[14];
  const float* bo = (const float*)d_in[15];
  float* out = (float*)d_out;

  char* w = (char*)d_ws;
  const size_t SEQ8_BYTES = (size_t)T_ * B_ * H_;              // 80 MB fp8
  const size_t W8_BYTES = 512 * 128 + 3 * 512 * 512;           // 832 KB
  const size_t U8_BYTES = 4 * 512 * 512;                       // 1 MB
  const size_t XWB = (size_t)TC_ * B_ * H_ * 2;                // 16 MB bf16
  const bool wf = ws_size >= SEQ8_BYTES + W8_BYTES + U8_BYTES + 4 * XWB;  // ~146 MB

  unsigned char* SEQ8 = (unsigned char*)w;
  unsigned char* W8[4];
  W8[0] = (unsigned char*)(w + SEQ8_BYTES);
  W8[1] = W8[0] + 512 * 128;
  W8[2] = W8[1] + 512 * 512;
  W8[3] = W8[2] + 512 * 512;
  unsigned char* Up[4];
  Up[0] = W8[3] + 512 * 512;
  Up[1] = Up[0] + 512 * 512;
  Up[2] = Up[1] + 512 * 512;
  Up[3] = Up[2] + 512 * 512;
  char* bankbase = w + SEQ8_BYTES + W8_BYTES + U8_BYTES;
  bf16* BANK[4];
  for (int i = 0; i < 4; i++) BANK[i] = (bf16*)(bankbase + (size_t)i * XWB);

  {
    WConv wc{};
    UConv uc{};
    for (int i = 0; i < 4; i++) {
      wc.src[i] = Ws[i]; wc.dst[i] = W8[i];
      wc.K[i] = (i == 0) ? 100 : 512;
      wc.Kp[i] = (i == 0) ? 128 : 512;
      uc.src[i] = Us[i]; uc.dst[i] = Up[i];
    }
    convert_weight_all<<<dim3(128, 4), 256, 0, stream>>>(wc);
    convert_u_all<<<dim3(128, 4), 256, 0, stream>>>(uc);
  }

  if (wf) {
    // layer-wavefront: round r = gemm then rnn for tasks (l, c=r-l), bank per layer.
    for (int r = 0; r <= NC_ - 1 + L_ - 1; r++) {
      GemmTasks gt{};
      RnnTasks rt{};
      int n = 0;
      int lmin = r - (NC_ - 1); if (lmin < 0) lmin = 0;
      int lmax = r < L_ - 1 ? r : L_ - 1;
      for (int l = lmin; l <= lmax; l++) {
        int c = r - l;
        bf16* xb = BANK[l];
        gt.A[n] = SEQ8 + (size_t)c * TC_ * B_ * H_;
        gt.Bt[n] = W8[l];
        gt.C[n] = xb;
        gt.kind[n] = (l == 0) ? 1 : 2;
        gt.t0[n] = c * TC_;
        rt.xwc[n] = xb;
        rt.U8[n] = Up[l];
        rt.bias[n] = bs[l];
        rt.t0[n] = c * TC_;
        rt.first[n] = (c == 0) ? 1 : 0;
        n++;
      }
      gemm_multi<<<n * 512, 256, 0, stream>>>(gt, tokens, emb);
      rnn_multi<<<n * 128, 1024, 0, stream>>>(rt, SEQ8);
    }
  } else {
    // serial fallback: 2 banks
    for (int l = 0; l < L_; l++) {
      for (int c = 0; c < NC_; c++) {
        bf16* xb = BANK[c & 1];
        GemmTasks gt{};
        RnnTasks rt{};
        gt.A[0] = SEQ8 + (size_t)c * TC_ * B_ * H_;
        gt.Bt[0] = W8[l];
        gt.C[0] = xb;
        gt.kind[0] = (l == 0) ? 1 : 2;
        gt.t0[0] = c * TC_;
        rt.xwc[0] = xb;
        rt.U8[0] = Up[l];
        rt.bias[0] = bs[l];
        rt.t0[0] = c * TC_;
        rt.first[0] = (c == 0) ? 1 : 0;
        gemm_multi<<<512, 256, 0, stream>>>(gt, tokens, emb);
        rnn_multi<<<128, 1024, 0, stream>>>(rt, SEQ8);
      }
    }
  }

  head_kernel<<<B_ / 4, 256, 0, stream>>>(SEQ8, Wo, bo, out);
}